// Round 14
// baseline (242.785 us; speedup 1.0000x reference)
//
#include <hip/hip_runtime.h>

#define DD 8
#define HW 16384
#define KK 256
#define NPIX 524288
#define NBLK 1024                      // 512 px per block, 2 px/thread (A/B)

#define Y_OFF    4194304UL             // B*D*H*W
#define REP_OFF  4718592UL             // + B*H*W
#define LOSS_OFF 138936320UL           // + B*H*W*K

typedef float f4 __attribute__((ext_vector_type(4)));

// LDS-only barrier: orders LDS (lgkmcnt) across waves WITHOUT draining the
// nt-store queue (vmcnt) — in-flight one-hot stores keep streaming.
__device__ __forceinline__ void lds_barrier() {
    asm volatile("s_waitcnt lgkmcnt(0)\n\ts_barrier" ::: "memory");
}

// ---- fused: free-running waves (R12 core) + last-block finalize ----
__global__ __launch_bounds__(256) void vq_fused_kernel(
    const float* __restrict__ q, const float* __restrict__ cb,
    float* __restrict__ emb, float* __restrict__ yf, float* __restrict__ rep,
    int* __restrict__ hist, float* __restrict__ partial, int* __restrict__ done,
    float* __restrict__ outp)
{
    __shared__ float sc2[KK];
    __shared__ int   syA[256];
    __shared__ int   syB[256];
    __shared__ int   shist[KK];
    __shared__ float swred[4];
    __shared__ int   sticket;

    const int tid  = threadIdx.x;
    const int wid  = tid >> 6;
    const int lane = tid & 63;
    shist[tid] = 0;

    {   // ||c||^2 in-block (same expression/bits as prior rounds)
        const f4 c01 = *(const f4*)(cb + tid*8);
        const f4 c23 = *(const f4*)(cb + tid*8 + 4);
        sc2[tid] = ((c01.x*c01.x + c01.y*c01.y) + (c01.z*c01.z + c01.w*c01.w))
                 + ((c23.x*c23.x + c23.y*c23.y) + (c23.z*c23.z + c23.w*c23.w));
    }

    const int pixBase = blockIdx.x << 9;     // 512 consecutive pixels, one image
    const int b    = pixBase >> 14;
    const int hw0  = pixBase & (HW - 1);
    const int hwA  = hw0 + tid;
    const int hwB2 = hw0 + 256 + tid;
    const float* qb = q + (size_t)b * (DD*HW);
    float* eb = emb + (size_t)b * (DD*HW);

    float xsA[DD], xsB[DD];
#pragma unroll
    for (int d = 0; d < DD; ++d) xsA[d] = qb[d*HW + hwA];
#pragma unroll
    for (int d = 0; d < DD; ++d) xsB[d] = qb[d*HW + hwB2];

    const float xnA = ((xsA[0]*xsA[0] + xsA[1]*xsA[1]) + (xsA[2]*xsA[2] + xsA[3]*xsA[3]))
                    + ((xsA[4]*xsA[4] + xsA[5]*xsA[5]) + (xsA[6]*xsA[6] + xsA[7]*xsA[7]));
    const float xnB = ((xsB[0]*xsB[0] + xsB[1]*xsB[1]) + (xsB[2]*xsB[2] + xsB[3]*xsB[3]))
                    + ((xsB[4]*xsB[4] + xsB[5]*xsB[5]) + (xsB[6]*xsB[6] + xsB[7]*xsB[7]));

    __syncthreads();   // sc2 + shist ready (no stores in flight yet)

    // ---- phase 1: argmax A (t = (x2-2xc)+c2, strict <  ==  ref -0.5*t, strict >) ----
    float bestA = 3.4e38f;
    int   yA    = 0;
#pragma unroll 4
    for (int k = 0; k < KK; ++k) {
        const f4 c01 = *(const f4*)(cb + (k << 3));   // lane-invariant -> s_load
        const f4 c23 = *(const f4*)(cb + (k << 3) + 4);
        const float c2k = sc2[k];
        float dot = 0.f;
        dot = fmaf(xsA[0], c01.x, dot);
        dot = fmaf(xsA[1], c01.y, dot);
        dot = fmaf(xsA[2], c01.z, dot);
        dot = fmaf(xsA[3], c01.w, dot);
        dot = fmaf(xsA[4], c23.x, dot);
        dot = fmaf(xsA[5], c23.y, dot);
        dot = fmaf(xsA[6], c23.z, dot);
        dot = fmaf(xsA[7], c23.w, dot);
        const float t = (xnA - 2.0f*dot) + c2k;
        if (t < bestA) { bestA = t; yA = k; }
    }

    float err = 0.f;
    {
        const f4 cy01 = *(const f4*)(cb + (yA << 3));
        const f4 cy23 = *(const f4*)(cb + (yA << 3) + 4);
        const float cyv[DD] = {cy01.x, cy01.y, cy01.z, cy01.w,
                               cy23.x, cy23.y, cy23.z, cy23.w};
#pragma unroll
        for (int d = 0; d < DD; ++d) {
            eb[d*HW + hwA] = cyv[d];
            const float dd = cyv[d] - xsA[d];
            err = fmaf(dd, dd, err);
        }
    }
    yf[pixBase + tid] = (float)yA;
    syA[tid] = yA;                      // read back only by THIS wave — no barrier
    atomicAdd(&shist[yA], 1);

    // ---- phase 2: argmax B interleaved with A's folded one-hot streaming ----
    float bestB = 3.4e38f;
    int   yB    = 0;
    f4* repA = (f4*)rep + (((size_t)(pixBase + (wid << 6))) << 6) + lane;
    const int b4 = lane << 2;
    for (int c = 0; c < 64; ++c) {
#pragma unroll
        for (int j = 0; j < 4; ++j) {
            const int k = (c << 2) + j;
            const f4 c01 = *(const f4*)(cb + (k << 3));
            const f4 c23 = *(const f4*)(cb + (k << 3) + 4);
            const float c2k = sc2[k];
            float dot = 0.f;
            dot = fmaf(xsB[0], c01.x, dot);
            dot = fmaf(xsB[1], c01.y, dot);
            dot = fmaf(xsB[2], c01.z, dot);
            dot = fmaf(xsB[3], c01.w, dot);
            dot = fmaf(xsB[4], c23.x, dot);
            dot = fmaf(xsB[5], c23.y, dot);
            dot = fmaf(xsB[6], c23.z, dot);
            dot = fmaf(xsB[7], c23.w, dot);
            const float t = (xnB - 2.0f*dot) + c2k;
            if (t < bestB) { bestB = t; yB = k; }
        }
        const int ya = syA[(wid << 6) + c];   // own-wave LDS broadcast
        f4 v;
        v.x = (ya == b4    ) ? 1.0f : 0.0f;
        v.y = (ya == b4 + 1) ? 1.0f : 0.0f;
        v.z = (ya == b4 + 2) ? 1.0f : 0.0f;
        v.w = (ya == b4 + 3) ? 1.0f : 0.0f;
        __builtin_nontemporal_store(v, repA + ((size_t)c << 6));
    }

    {
        const f4 cy01 = *(const f4*)(cb + (yB << 3));
        const f4 cy23 = *(const f4*)(cb + (yB << 3) + 4);
        const float cyv[DD] = {cy01.x, cy01.y, cy01.z, cy01.w,
                               cy23.x, cy23.y, cy23.z, cy23.w};
#pragma unroll
        for (int d = 0; d < DD; ++d) {
            eb[d*HW + hwB2] = cyv[d];
            const float dd = cyv[d] - xsB[d];
            err = fmaf(dd, dd, err);
        }
    }
    yf[pixBase + 256 + tid] = (float)yB;
    syB[tid] = yB;                      // own-wave only
    atomicAdd(&shist[yB], 1);

    // ---- phase 3: stream B's folded rows (own-wave sy, no barrier) ----
    {
        f4* repB = (f4*)rep + (((size_t)(pixBase + 256 + (wid << 6))) << 6) + lane;
        for (int c = 0; c < 64; ++c) {
            const int yb2 = syB[(wid << 6) + c];
            f4 v;
            v.x = (yb2 == b4    ) ? 1.0f : 0.0f;
            v.y = (yb2 == b4 + 1) ? 1.0f : 0.0f;
            v.z = (yb2 == b4 + 2) ? 1.0f : 0.0f;
            v.w = (yb2 == b4 + 3) ? 1.0f : 0.0f;
            __builtin_nontemporal_store(v, repB + ((size_t)c << 6));
        }
    }

    // deterministic wave reduction of err (both pixels)
#pragma unroll
    for (int off = 32; off; off >>= 1)
        err += __shfl_down(err, off, 64);
    if (lane == 0) swred[wid] = err;

    lds_barrier();   // shist atomics + swred visible; nt stores keep draining

    if (tid == 0)
        partial[blockIdx.x] = (swred[0] + swred[1]) + (swred[2] + swred[3]);
    atomicAdd(&hist[tid], shist[tid]);

    // ---- last-block finalize (device-scope handoff, no extra dispatch) ----
    __threadfence();                       // partial store + hist atomics visible
    if (tid == 0)
        sticket = atomicAdd(done, 1);
    __syncthreads();
    if (sticket != NBLK - 1) return;

    // we are the last block: every partial[]/hist[] contribution is globally done
    {
        __shared__ double sred[4];
        __shared__ double shy[4];

        double s = 0.0;
#pragma unroll
        for (int i = 0; i < 4; ++i)
            s += (double)__hip_atomic_load(&partial[tid + (i << 8)],
                                           __ATOMIC_RELAXED, __HIP_MEMORY_SCOPE_AGENT);
#pragma unroll
        for (int off = 32; off; off >>= 1)
            s += __shfl_down(s, off, 64);
        if (lane == 0) sred[wid] = s;

        const int c = __hip_atomic_load(&hist[tid],
                                        __ATOMIC_RELAXED, __HIP_MEMORY_SCOPE_AGENT);
        float py = (float)c * (1.0f / 524288.0f);
        double ht = (double)(py * log2f(py + 1e-10f));
#pragma unroll
        for (int off = 32; off; off >>= 1)
            ht += __shfl_down(ht, off, 64);
        if (lane == 0) shy[wid] = ht;
        __syncthreads();

        if (tid == 0) {
            double S  = (sred[0] + sred[1]) + (sred[2] + sred[3]);
            double Hy = (shy[0]  + shy[1])  + (shy[2]  + shy[3]);
            // loss = 0.5*(0.25*S/4096 + S/4096) = 0.625 * S / 4096
            outp[0] = (float)(0.625 * S / 4096.0);
            outp[1] = (float)(-Hy);
            outp[2] = 0.0f;
        }
    }
}

extern "C" void kernel_launch(void* const* d_in, const int* in_sizes, int n_in,
                              void* d_out, int out_size, void* d_ws, size_t ws_size,
                              hipStream_t stream)
{
    const float* q  = (const float*)d_in[0];
    const float* cb = (const float*)d_in[1];
    float* out = (float*)d_out;

    float* emb = out;                     // [B,D,H,W]
    float* yf  = out + Y_OFF;             // [B,H,W] as float
    float* rep = out + REP_OFF;           // [B,H,W,K]
    float* sc  = out + LOSS_OFF;          // loss, Hy, Hyx

    float* w       = (float*)d_ws;
    int*   hist    = (int*)w;             // [0..255]   histogram bins
    int*   done    = (int*)w + 256;       // [256]      completion ticket
    float* partial = w + 320;             // [320..1343] per-block loss partials

    hipMemsetAsync(d_ws, 0, 1280, stream);   // zero hist + done
    vq_fused_kernel<<<NBLK, 256, 0, stream>>>(q, cb, emb, yf, rep,
                                              hist, partial, done, sc);
}

// Round 15
// 126.223 us; speedup vs baseline: 1.9235x; 1.9235x over previous
//
#include <hip/hip_runtime.h>

#define DD 8
#define HW 16384
#define KK 256
#define NPIX 524288
#define NBLK 2048                      // 256 px per block, 1 px/thread, per-wave autonomy

#define Y_OFF    4194304UL             // B*D*H*W
#define REP_OFF  4718592UL             // + B*H*W
#define LOSS_OFF 138936320UL           // + B*H*W*K

typedef float f4 __attribute__((ext_vector_type(4)));

// LDS-only barrier: orders LDS (lgkmcnt) across waves WITHOUT draining the
// nt-store queue (vmcnt) — in-flight one-hot stores keep streaming.
__device__ __forceinline__ void lds_barrier() {
    asm volatile("s_waitcnt lgkmcnt(0)\n\ts_barrier" ::: "memory");
}

// ---- fused: fully free-running waves — each wave scans 64 px, then streams them ----
__global__ __launch_bounds__(256) void vq_fused_kernel(
    const float* __restrict__ q, const float* __restrict__ cb,
    float* __restrict__ emb, float* __restrict__ yf, float* __restrict__ rep,
    int* __restrict__ hist, float* __restrict__ partial)
{
    __shared__ float sc2[KK];
    __shared__ int   sy[256];
    __shared__ int   shist[KK];

    const int tid  = threadIdx.x;
    const int wid  = tid >> 6;
    const int lane = tid & 63;
    shist[tid] = 0;

    {   // ||c||^2 in-block (same expression/bits as prior rounds)
        const f4 c01 = *(const f4*)(cb + tid*8);
        const f4 c23 = *(const f4*)(cb + tid*8 + 4);
        sc2[tid] = ((c01.x*c01.x + c01.y*c01.y) + (c01.z*c01.z + c01.w*c01.w))
                 + ((c23.x*c23.x + c23.y*c23.y) + (c23.z*c23.z + c23.w*c23.w));
    }

    const int pixBase = blockIdx.x << 8;     // 256 consecutive pixels, one image
    const int b   = pixBase >> 14;
    const int hwB = pixBase & (HW - 1);
    const int hw  = hwB + tid;
    const float* qb = q + (size_t)b * (DD*HW);
    float* eb = emb + (size_t)b * (DD*HW);

    float xs[DD];
#pragma unroll
    for (int d = 0; d < DD; ++d) xs[d] = qb[d*HW + hw];
    const float xn = ((xs[0]*xs[0] + xs[1]*xs[1]) + (xs[2]*xs[2] + xs[3]*xs[3]))
                   + ((xs[4]*xs[4] + xs[5]*xs[5]) + (xs[6]*xs[6] + xs[7]*xs[7]));

    __syncthreads();   // sc2 + shist ready (no stores in flight yet)

    // ---- scan: t = (x2-2xc)+c2 with strict <  ==  reference -0.5*t with strict > ----
    float best = 3.4e38f;
    int   yb   = 0;
#pragma unroll 4
    for (int k = 0; k < KK; ++k) {
        const f4 c01 = *(const f4*)(cb + (k << 3));   // lane-invariant -> s_load
        const f4 c23 = *(const f4*)(cb + (k << 3) + 4);
        const float c2k = sc2[k];
        float dot = 0.f;
        dot = fmaf(xs[0], c01.x, dot);
        dot = fmaf(xs[1], c01.y, dot);
        dot = fmaf(xs[2], c01.z, dot);
        dot = fmaf(xs[3], c01.w, dot);
        dot = fmaf(xs[4], c23.x, dot);
        dot = fmaf(xs[5], c23.y, dot);
        dot = fmaf(xs[6], c23.z, dot);
        dot = fmaf(xs[7], c23.w, dot);
        const float t = (xn - 2.0f*dot) + c2k;
        if (t < best) { best = t; yb = k; }   // first index wins ties
    }

    // per-pixel outputs: emb (nt), err, y (nt), sy (own-wave)
    float err = 0.f;
    {
        const f4 cy01 = *(const f4*)(cb + (yb << 3));
        const f4 cy23 = *(const f4*)(cb + (yb << 3) + 4);
        const float cyv[DD] = {cy01.x, cy01.y, cy01.z, cy01.w,
                               cy23.x, cy23.y, cy23.z, cy23.w};
#pragma unroll
        for (int d = 0; d < DD; ++d) {
            __builtin_nontemporal_store(cyv[d], eb + d*HW + hw);
            const float dd = cyv[d] - xs[d];
            err = fmaf(dd, dd, err);
        }
    }
    __builtin_nontemporal_store((float)yb, yf + pixBase + tid);
    sy[tid] = yb;                       // read back only by THIS wave
    atomicAdd(&shist[yb], 1);

    // ---- stream this wave's 64 folded one-hot rows (no barrier needed) ----
    {
        f4* repw = (f4*)rep + (((size_t)(pixBase + (wid << 6))) << 6) + lane;
        const int b4 = lane << 2;
        for (int c = 0; c < 64; ++c) {
            const int ya = sy[(wid << 6) + c];   // own-wave LDS broadcast
            f4 v;
            v.x = (ya == b4    ) ? 1.0f : 0.0f;
            v.y = (ya == b4 + 1) ? 1.0f : 0.0f;
            v.z = (ya == b4 + 2) ? 1.0f : 0.0f;
            v.w = (ya == b4 + 3) ? 1.0f : 0.0f;
            __builtin_nontemporal_store(v, repw + ((size_t)c << 6));
        }
    }

    // per-wave deterministic err reduction -> per-wave partial (no cross-wave barrier)
#pragma unroll
    for (int off = 32; off; off >>= 1)
        err += __shfl_down(err, off, 64);
    if (lane == 0)
        partial[(blockIdx.x << 2) + wid] = err;

    lds_barrier();   // shist atomics visible; nt stores keep draining
    atomicAdd(&hist[tid], shist[tid]);
}

// ---------------- finalize scalars ----------------
__global__ __launch_bounds__(256) void vq_final_kernel(
    const float* __restrict__ partial, const int* __restrict__ hist,
    float* __restrict__ outp)
{
    const int tid = threadIdx.x;
    __shared__ double sred[4];
    __shared__ double shy[4];

    double s = 0.0;
#pragma unroll
    for (int i = 0; i < 32; ++i) s += (double)partial[tid * 32 + i];
#pragma unroll
    for (int off = 32; off; off >>= 1)
        s += __shfl_down(s, off, 64);
    if ((tid & 63) == 0) sred[tid >> 6] = s;

    float c  = (float)hist[tid];
    float py = c * (1.0f / 524288.0f);
    double ht = (double)(py * log2f(py + 1e-10f));
#pragma unroll
    for (int off = 32; off; off >>= 1)
        ht += __shfl_down(ht, off, 64);
    if ((tid & 63) == 0) shy[tid >> 6] = ht;
    __syncthreads();

    if (tid == 0) {
        double S  = (sred[0] + sred[1]) + (sred[2] + sred[3]);
        double Hy = (shy[0]  + shy[1])  + (shy[2]  + shy[3]);
        // loss = 0.5*(0.25*S/4096 + S/4096) = 0.625 * S / 4096
        outp[0] = (float)(0.625 * S / 4096.0);
        outp[1] = (float)(-Hy);
        outp[2] = 0.0f;
    }
}

extern "C" void kernel_launch(void* const* d_in, const int* in_sizes, int n_in,
                              void* d_out, int out_size, void* d_ws, size_t ws_size,
                              hipStream_t stream)
{
    const float* q  = (const float*)d_in[0];
    const float* cb = (const float*)d_in[1];
    float* out = (float*)d_out;

    float* emb = out;                     // [B,D,H,W]
    float* yf  = out + Y_OFF;             // [B,H,W] as float
    float* rep = out + REP_OFF;           // [B,H,W,K]
    float* sc  = out + LOSS_OFF;          // loss, Hy, Hyx

    float* w       = (float*)d_ws;
    int*   hist    = (int*)w;             // 256 ints
    float* partial = w + 256;             // 8192 floats (per-wave partials)

    hipMemsetAsync(hist, 0, 1024, stream);   // zero hist
    vq_fused_kernel<<<NBLK, 256, 0, stream>>>(q, cb, emb, yf, rep, hist, partial);
    vq_final_kernel<<<1, 256, 0, stream>>>(partial, hist, sc);
}

// Round 16
// 123.077 us; speedup vs baseline: 1.9726x; 1.0256x over previous
//
#include <hip/hip_runtime.h>

#define DD 8
#define HW 16384
#define KK 256
#define NPIX 524288
#define NBLK 1024                      // 512 px per block, 2 px/thread (A/B)

#define Y_OFF    4194304UL             // B*D*H*W
#define REP_OFF  4718592UL             // + B*H*W
#define LOSS_OFF 138936320UL           // + B*H*W*K

typedef float f4 __attribute__((ext_vector_type(4)));

// ---- fused: R8 lockstep A/B pipeline + nt emb/yf + unrolled streams ----
__global__ __launch_bounds__(256) void vq_fused_kernel(
    const float* __restrict__ q, const float* __restrict__ cb,
    float* __restrict__ emb, float* __restrict__ yf, float* __restrict__ rep,
    int* __restrict__ hist, float* __restrict__ partial)
{
    __shared__ float sc2[KK];
    __shared__ int   syA[256];
    __shared__ int   syB[256];
    __shared__ int   shist[KK];
    __shared__ float swred[4];

    const int tid  = threadIdx.x;
    const int wid  = tid >> 6;
    const int lane = tid & 63;
    shist[tid] = 0;

    {   // ||c||^2 in-block (same expression/bits as prior rounds)
        const f4 c01 = *(const f4*)(cb + tid*8);
        const f4 c23 = *(const f4*)(cb + tid*8 + 4);
        sc2[tid] = ((c01.x*c01.x + c01.y*c01.y) + (c01.z*c01.z + c01.w*c01.w))
                 + ((c23.x*c23.x + c23.y*c23.y) + (c23.z*c23.z + c23.w*c23.w));
    }

    const int pixBase = blockIdx.x << 9;     // 512 consecutive pixels, one image
    const int b    = pixBase >> 14;
    const int hw0  = pixBase & (HW - 1);
    const int hwA  = hw0 + tid;
    const int hwB2 = hw0 + 256 + tid;
    const float* qb = q + (size_t)b * (DD*HW);
    float* eb = emb + (size_t)b * (DD*HW);

    // load both pixels up front (B's latency hides under phase-1 compute)
    float xsA[DD], xsB[DD];
#pragma unroll
    for (int d = 0; d < DD; ++d) xsA[d] = qb[d*HW + hwA];
#pragma unroll
    for (int d = 0; d < DD; ++d) xsB[d] = qb[d*HW + hwB2];

    const float xnA = ((xsA[0]*xsA[0] + xsA[1]*xsA[1]) + (xsA[2]*xsA[2] + xsA[3]*xsA[3]))
                    + ((xsA[4]*xsA[4] + xsA[5]*xsA[5]) + (xsA[6]*xsA[6] + xsA[7]*xsA[7]));
    const float xnB = ((xsB[0]*xsB[0] + xsB[1]*xsB[1]) + (xsB[2]*xsB[2] + xsB[3]*xsB[3]))
                    + ((xsB[4]*xsB[4] + xsB[5]*xsB[5]) + (xsB[6]*xsB[6] + xsB[7]*xsB[7]));

    __syncthreads();   // sc2 + shist ready

    // ---- phase 1: argmax A (t = (x2-2xc)+c2, strict <  ==  ref -0.5*t, strict >) ----
    float bestA = 3.4e38f;
    int   yA    = 0;
#pragma unroll 4
    for (int k = 0; k < KK; ++k) {
        const f4 c01 = *(const f4*)(cb + (k << 3));   // lane-invariant -> s_load
        const f4 c23 = *(const f4*)(cb + (k << 3) + 4);
        const float c2k = sc2[k];
        float dot = 0.f;
        dot = fmaf(xsA[0], c01.x, dot);
        dot = fmaf(xsA[1], c01.y, dot);
        dot = fmaf(xsA[2], c01.z, dot);
        dot = fmaf(xsA[3], c01.w, dot);
        dot = fmaf(xsA[4], c23.x, dot);
        dot = fmaf(xsA[5], c23.y, dot);
        dot = fmaf(xsA[6], c23.z, dot);
        dot = fmaf(xsA[7], c23.w, dot);
        const float t = (xnA - 2.0f*dot) + c2k;
        if (t < bestA) { bestA = t; yA = k; }
    }

    float err = 0.f;
    {
        const f4 cy01 = *(const f4*)(cb + (yA << 3));
        const f4 cy23 = *(const f4*)(cb + (yA << 3) + 4);
        const float cyv[DD] = {cy01.x, cy01.y, cy01.z, cy01.w,
                               cy23.x, cy23.y, cy23.z, cy23.w};
#pragma unroll
        for (int d = 0; d < DD; ++d) {
            __builtin_nontemporal_store(cyv[d], eb + d*HW + hwA);
            const float dd = cyv[d] - xsA[d];
            err = fmaf(dd, dd, err);
        }
    }
    __builtin_nontemporal_store((float)yA, yf + pixBase + tid);
    syA[tid] = yA;
    atomicAdd(&shist[yA], 1);

    __syncthreads();   // syA ready

    // ---- phase 2: argmax B interleaved with A's folded one-hot streaming ----
    float bestB = 3.4e38f;
    int   yB    = 0;
    f4* repA = (f4*)rep + (((size_t)(pixBase + (wid << 6))) << 6) + lane;
    const int b4 = lane << 2;
    for (int c = 0; c < 64; c += 2) {
        // two independent sy reads up front (ILP for the LDS pipe)
        const int ya0 = syA[(wid << 6) + c];
        const int ya1 = syA[(wid << 6) + c + 1];
#pragma unroll
        for (int j = 0; j < 8; ++j) {
            const int k = (c << 2) + j;
            const f4 c01 = *(const f4*)(cb + (k << 3));
            const f4 c23 = *(const f4*)(cb + (k << 3) + 4);
            const float c2k = sc2[k];
            float dot = 0.f;
            dot = fmaf(xsB[0], c01.x, dot);
            dot = fmaf(xsB[1], c01.y, dot);
            dot = fmaf(xsB[2], c01.z, dot);
            dot = fmaf(xsB[3], c01.w, dot);
            dot = fmaf(xsB[4], c23.x, dot);
            dot = fmaf(xsB[5], c23.y, dot);
            dot = fmaf(xsB[6], c23.z, dot);
            dot = fmaf(xsB[7], c23.w, dot);
            const float t = (xnB - 2.0f*dot) + c2k;
            if (t < bestB) { bestB = t; yB = k; }
        }
        f4 v0, v1;
        v0.x = (ya0 == b4    ) ? 1.0f : 0.0f;
        v0.y = (ya0 == b4 + 1) ? 1.0f : 0.0f;
        v0.z = (ya0 == b4 + 2) ? 1.0f : 0.0f;
        v0.w = (ya0 == b4 + 3) ? 1.0f : 0.0f;
        v1.x = (ya1 == b4    ) ? 1.0f : 0.0f;
        v1.y = (ya1 == b4 + 1) ? 1.0f : 0.0f;
        v1.z = (ya1 == b4 + 2) ? 1.0f : 0.0f;
        v1.w = (ya1 == b4 + 3) ? 1.0f : 0.0f;
        __builtin_nontemporal_store(v0, repA + ((size_t)c << 6));
        __builtin_nontemporal_store(v1, repA + ((size_t)(c + 1) << 6));
    }

    {
        const f4 cy01 = *(const f4*)(cb + (yB << 3));
        const f4 cy23 = *(const f4*)(cb + (yB << 3) + 4);
        const float cyv[DD] = {cy01.x, cy01.y, cy01.z, cy01.w,
                               cy23.x, cy23.y, cy23.z, cy23.w};
#pragma unroll
        for (int d = 0; d < DD; ++d) {
            __builtin_nontemporal_store(cyv[d], eb + d*HW + hwB2);
            const float dd = cyv[d] - xsB[d];
            err = fmaf(dd, dd, err);
        }
    }
    __builtin_nontemporal_store((float)yB, yf + pixBase + 256 + tid);
    syB[tid] = yB;
    atomicAdd(&shist[yB], 1);

    // deterministic wave reduction of err (both pixels; finalized pre-barrier)
#pragma unroll
    for (int off = 32; off; off >>= 1)
        err += __shfl_down(err, off, 64);
    if (lane == 0) swred[wid] = err;

    __syncthreads();   // syB, shist, swred ready

    if (tid == 0)
        partial[blockIdx.x] = (swred[0] + swred[1]) + (swred[2] + swred[3]);
    atomicAdd(&hist[tid], shist[tid]);

    // ---- phase 3: stream B's folded rows (tight, store-bound, 2x unrolled) ----
    f4* repB = (f4*)rep + (((size_t)(pixBase + 256 + (wid << 6))) << 6) + lane;
    for (int c = 0; c < 64; c += 2) {
        const int y0 = syB[(wid << 6) + c];
        const int y1 = syB[(wid << 6) + c + 1];
        f4 v0, v1;
        v0.x = (y0 == b4    ) ? 1.0f : 0.0f;
        v0.y = (y0 == b4 + 1) ? 1.0f : 0.0f;
        v0.z = (y0 == b4 + 2) ? 1.0f : 0.0f;
        v0.w = (y0 == b4 + 3) ? 1.0f : 0.0f;
        v1.x = (y1 == b4    ) ? 1.0f : 0.0f;
        v1.y = (y1 == b4 + 1) ? 1.0f : 0.0f;
        v1.z = (y1 == b4 + 2) ? 1.0f : 0.0f;
        v1.w = (y1 == b4 + 3) ? 1.0f : 0.0f;
        __builtin_nontemporal_store(v0, repB + ((size_t)c << 6));
        __builtin_nontemporal_store(v1, repB + ((size_t)(c + 1) << 6));
    }
}

// ---------------- finalize scalars ----------------
__global__ __launch_bounds__(256) void vq_final_kernel(
    const float* __restrict__ partial, const int* __restrict__ hist,
    float* __restrict__ outp)
{
    const int tid = threadIdx.x;
    __shared__ double sred[4];
    __shared__ double shy[4];

    double s = 0.0;
#pragma unroll
    for (int i = 0; i < 4; ++i) s += (double)partial[tid + (i << 8)];
#pragma unroll
    for (int off = 32; off; off >>= 1)
        s += __shfl_down(s, off, 64);
    if ((tid & 63) == 0) sred[tid >> 6] = s;

    float c  = (float)hist[tid];
    float py = c * (1.0f / 524288.0f);
    double ht = (double)(py * log2f(py + 1e-10f));
#pragma unroll
    for (int off = 32; off; off >>= 1)
        ht += __shfl_down(ht, off, 64);
    if ((tid & 63) == 0) shy[tid >> 6] = ht;
    __syncthreads();

    if (tid == 0) {
        double S  = (sred[0] + sred[1]) + (sred[2] + sred[3]);
        double Hy = (shy[0]  + shy[1])  + (shy[2]  + shy[3]);
        // loss = 0.5*(0.25*S/4096 + S/4096) = 0.625 * S / 4096
        outp[0] = (float)(0.625 * S / 4096.0);
        outp[1] = (float)(-Hy);
        outp[2] = 0.0f;
    }
}

extern "C" void kernel_launch(void* const* d_in, const int* in_sizes, int n_in,
                              void* d_out, int out_size, void* d_ws, size_t ws_size,
                              hipStream_t stream)
{
    const float* q  = (const float*)d_in[0];
    const float* cb = (const float*)d_in[1];
    float* out = (float*)d_out;

    float* emb = out;                     // [B,D,H,W]
    float* yf  = out + Y_OFF;             // [B,H,W] as float
    float* rep = out + REP_OFF;           // [B,H,W,K]
    float* sc  = out + LOSS_OFF;          // loss, Hy, Hyx

    float* w       = (float*)d_ws;
    int*   hist    = (int*)w;             // 256 ints
    float* partial = w + 256;             // 1024 floats

    hipMemsetAsync(hist, 0, 1024, stream);   // zero hist
    vq_fused_kernel<<<NBLK, 256, 0, stream>>>(q, cb, emb, yf, rep, hist, partial);
    vq_final_kernel<<<1, 256, 0, stream>>>(partial, hist, sc);
}